// Round 2
// baseline (455.371 us; speedup 1.0000x reference)
//
#include <hip/hip_runtime.h>
#include <stdint.h>

#define EPSF 1e-5f

typedef _Float16 h8_t __attribute__((ext_vector_type(8)));
typedef float f4_t __attribute__((ext_vector_type(4)));

#define BB 64
#define CC 256
#define HH 32
#define WW 32
#define HP 34
#define WP 34
#define MTOT (BB*HH*WW)        // 65536
#define WELEMS (CC*CC*9)       // 589824
#define PADIMG (HP*WP*CC)      // halfwords per image
#define PADTOT (BB*PADIMG)     // 18939904 halfwords

// ---- stats layout (float offsets)
#define S_MAXABS 0
#define S_GSUM   1     // 64
#define S_SUM1   129
#define S_SQ1    130
#define S_SUM2   131
#define S_SQ2    132
#define S_M1     133
#define S_S1     134
#define S_M2     135
#define S_S2     136
#define S_PW1    137   // 3
#define S_PA1    140   // 3
#define S_PW2    143   // 3
#define S_PA2    146   // 3
#define S_INDCH  160   // 256
#define S_GATE   416   // 256
#define S_BN1SC  672   // 256
#define S_BN1SH  928   // 256
#define S_BN2SC  1184  // 256
#define S_BN2SH  1440  // 256

// ---- ws byte offsets
#define OFF_STATS 0
#define OFF_A1    8192
#define OFF_A2    (OFF_A1 + PADTOT*2)
#define OFF_W1T   (OFF_A2 + PADTOT*2)
#define OFF_W2T   (OFF_W1T + 9*CC*CC*2)

__device__ __forceinline__ void async_load16(void* lds, const void* g) {
  // direct global->LDS, 16B/lane; LDS dest = uniform base + lane*16
  __builtin_amdgcn_global_load_lds(
      reinterpret_cast<uint32_t __attribute__((address_space(1)))*>((uintptr_t)g),
      reinterpret_cast<uint32_t __attribute__((address_space(3)))*>((uint32_t)(uintptr_t)lds),
      16, 0, 0);
}

__device__ __forceinline__ float wave_sum(float v) {
  for (int o = 32; o; o >>= 1) v += __shfl_down(v, o);
  return v;
}
__device__ __forceinline__ float wave_max(float v) {
  for (int o = 32; o; o >>= 1) v = fmaxf(v, __shfl_down(v, o));
  return v;
}

// ---------------- stats: per-group |w1| sums + global maxabs ----------------
__global__ void k_groupstats(const float* __restrict__ w1, float* stats) {
  int g = blockIdx.x;  // 64 groups of 4 out-channels = 9216 contiguous floats
  const float* p = w1 + g * 9216;
  float s = 0.f, mx = 0.f;
  for (int i = threadIdx.x; i < 9216; i += 256) {
    float v = fabsf(p[i]);
    s += v; mx = fmaxf(mx, v);
  }
  s = wave_sum(s); mx = wave_max(mx);
  __shared__ float ls[4], lm[4];
  int lane = threadIdx.x & 63, w = threadIdx.x >> 6;
  if (lane == 0) { ls[w] = s; lm[w] = mx; }
  __syncthreads();
  if (threadIdx.x == 0) {
    float ss = ls[0] + ls[1] + ls[2] + ls[3];
    float mm = fmaxf(fmaxf(lm[0], lm[1]), fmaxf(lm[2], lm[3]));
    stats[S_GSUM + g] = ss;
    atomicMax((unsigned int*)(stats + S_MAXABS), __float_as_uint(mm));
  }
}

__device__ __forceinline__ void softmax3(const float* l, float* out) {
  float m = fmaxf(fmaxf(l[0], l[1]), l[2]);
  float e0 = expf(l[0] - m), e1 = expf(l[1] - m), e2 = expf(l[2] - m);
  float inv = 1.f / (e0 + e1 + e2);
  out[0] = e0 * inv; out[1] = e1 * inv; out[2] = e2 * inv;
}

// ---------------- indicator, gates, bn scale/shift, softmaxes ----------------
__global__ void k_prep(const float* thr_p,
                       const float* bn1g, const float* bn1b, const float* bn1m, const float* bn1v,
                       const float* bn2g, const float* bn2b, const float* bn2m, const float* bn2v,
                       const float* wl1, const float* al1, const float* wl2, const float* al2,
                       float* stats) {
  int t = threadIdx.x;
  float thr = thr_p[0];
  float maxab = stats[S_MAXABS];
  __shared__ float ind[64];
  if (t < 64) {
    float norm = stats[S_GSUM + t] / maxab / 9216.0f;
    float soft = 1.f / (1.f + expf(-(norm - thr)));
    float hard = (norm > thr) ? 1.f : 0.f;
    ind[t] = (hard - soft) + soft;   // STE forward value
  }
  __syncthreads();
  {
    float iv = ind[t >> 2];
    stats[S_INDCH + t] = iv;
    stats[S_GATE + t] = (iv > 0.f) ? 1.f : 0.f;
    float sc1 = bn1g[t] * (1.f / sqrtf(bn1v[t] + EPSF));
    stats[S_BN1SC + t] = sc1;
    stats[S_BN1SH + t] = bn1b[t] - bn1m[t] * sc1;
    float sc2 = bn2g[t] * (1.f / sqrtf(bn2v[t] + EPSF));
    stats[S_BN2SC + t] = sc2;
    stats[S_BN2SH + t] = bn2b[t] - bn2m[t] * sc2;
  }
  if (t == 0) {
    softmax3(wl1, stats + S_PW1);
    softmax3(al1, stats + S_PA1);
    softmax3(wl2, stats + S_PW2);
    softmax3(al2, stats + S_PA2);
  }
}

// ---------------- masked sum / sumsq for w1 (out-ch mask) and w2 (in-ch mask) ----------------
__global__ void k_masked(const float* __restrict__ w1, const float* __restrict__ w2,
                         float* stats) {
  const float* gate = stats + S_GATE;
  float s1 = 0.f, q1 = 0.f, s2 = 0.f, q2 = 0.f;
  for (int i = blockIdx.x * 256 + threadIdx.x; i < 2 * WELEMS; i += gridDim.x * 256) {
    if (i < WELEMS) {
      int o = i / 2304;
      float m = gate[o];
      float v = w1[i];
      s1 += m * v; q1 += m * v * v;
    } else {
      int j = i - WELEMS;
      int ic = (j / 9) & 255;
      float m = gate[ic];
      float v = w2[j];
      s2 += m * v; q2 += m * v * v;
    }
  }
  s1 = wave_sum(s1); q1 = wave_sum(q1); s2 = wave_sum(s2); q2 = wave_sum(q2);
  __shared__ float red[4][4];
  int lane = threadIdx.x & 63, w = threadIdx.x >> 6;
  if (lane == 0) { red[w][0] = s1; red[w][1] = q1; red[w][2] = s2; red[w][3] = q2; }
  __syncthreads();
  if (threadIdx.x == 0) {
    float a = 0, b = 0, c = 0, d = 0;
    for (int k = 0; k < 4; ++k) { a += red[k][0]; b += red[k][1]; c += red[k][2]; d += red[k][3]; }
    atomicAdd(stats + S_SUM1, a); atomicAdd(stats + S_SQ1, b);
    atomicAdd(stats + S_SUM2, c); atomicAdd(stats + S_SQ2, d);
  }
}

// ---------------- finalize masked mean/std (parallel gate-sum) ----------------
__global__ void k_final(float* stats) {
  int t = threadIdx.x;               // 256 threads
  float g = stats[S_GATE + t];
  g = wave_sum(g);
  __shared__ float red[4];
  int lane = t & 63, w = t >> 6;
  if (lane == 0) red[w] = g;
  __syncthreads();
  if (t == 0) {
    float ns = red[0] + red[1] + red[2] + red[3];
    float cnt = ns * 2304.0f;
    float m1 = stats[S_SUM1] / cnt;
    float v1 = (stats[S_SQ1] - cnt * m1 * m1) / (cnt - 1.0f);
    stats[S_M1] = m1; stats[S_S1] = sqrtf(fmaxf(v1, 0.f));
    float m2 = stats[S_SUM2] / cnt;
    float v2 = (stats[S_SQ2] - cnt * m2 * m2) / (cnt - 1.0f);
    stats[S_M2] = m2; stats[S_S2] = sqrtf(fmaxf(v2, 0.f));
  }
}

// ---------------- weight quant+mix -> fp16, layout [e][co][ci] ----------------
__global__ void k_wprep(const float* __restrict__ w1, const float* __restrict__ w2,
                        const float* __restrict__ stats,
                        _Float16* __restrict__ wt1, _Float16* __restrict__ wt2) {
  int t = blockIdx.x * 256 + threadIdx.x;   // 0 .. 2*WELEMS-1
  int which = (t >= WELEMS) ? 1 : 0;
  int r = which ? t - WELEMS : t;
  int e = r >> 16;
  int o = (r >> 8) & 255;
  int ci = r & 255;
  const float* w = which ? w2 : w1;
  float mean = stats[which ? S_M2 : S_M1];
  float sd = stats[which ? S_S2 : S_S1] + EPSF;
  const float* pw = stats + (which ? S_PW2 : S_PW1);
  float v = w[((o << 8) | ci) * 9 + e];
  float wn = fminf(fmaxf((v - mean) / sd, -1.f), 1.f);
  float u0 = rintf((wn + 1.f) * 0.5f * 3.f) / 3.f;
  float u1 = rintf((wn + 1.f) * 0.5f * 15.f) / 15.f;
  float u2 = rintf((wn + 1.f) * 0.5f * 255.f) / 255.f;
  float mix = pw[0] * (2.f * u0 - 1.f) + pw[1] * (2.f * u1 - 1.f) + pw[2] * (2.f * u2 - 1.f);
  (which ? wt2 : wt1)[r] = (_Float16)mix;
}

// ---------------- zero the 1-pixel borders of both padded act buffers ----------------
__global__ void k_borders(_Float16* a1, _Float16* a2) {
  int bid = blockIdx.x;            // 2 * 64 * 132 blocks
  _Float16* base = (bid >= BB * 132) ? a2 : a1;
  int r = (bid >= BB * 132) ? bid - BB * 132 : bid;
  int n = r / 132, b = r % 132;
  int yy, xx;
  if (b < 34)       { yy = 0;       xx = b; }
  else if (b < 68)  { yy = 33;      xx = b - 34; }
  else if (b < 100) { yy = b - 67;  xx = 0; }
  else              { yy = b - 99;  xx = 33; }
  uint64_t* p = (uint64_t*)(base + ((size_t)(n * HP + yy) * WP + xx) * CC);
  p[threadIdx.x] = 0ull;           // 64 threads * 8B = 512B = 256 fp16
}

// ---------------- bn1+relu+quant-mix -> fp16 padded NHWC ----------------
#define APR_STRIDE 264
__global__ void k_aprep(const float* __restrict__ xin, const float* __restrict__ stats,
                        _Float16* __restrict__ a1) {
  __shared__ __attribute__((aligned(16))) _Float16 lds[32 * APR_STRIDE];
  int n = blockIdx.x >> 5, y = blockIdx.x & 31;
  int t = threadIdx.x;
  int x = t & 31, c0 = t >> 5;
  float pa0 = stats[S_PA1], pa1 = stats[S_PA1 + 1], pa2 = stats[S_PA1 + 2];
  const float* bsc = stats + S_BN1SC;
  const float* bsh = stats + S_BN1SH;
  for (int cc = 0; cc < 32; ++cc) {
    int c = cc * 8 + c0;
    float v = xin[((n * CC + c) * HH + y) * WW + x];
    v = fmaxf(v * bsc[c] + bsh[c], 0.f);
    float cl = fminf(v, 1.f);
    float q = pa0 * (rintf(cl * 3.f) / 3.f) + pa1 * (rintf(cl * 15.f) / 15.f)
            + pa2 * (rintf(cl * 255.f) / 255.f);
    lds[x * APR_STRIDE + c] = (_Float16)q;
  }
  __syncthreads();
  _Float16* orow = a1 + ((size_t)(n * HP + (y + 1)) * WP + 1) * CC;
  for (int it = 0; it < 4; ++it) {
    int qid = it * 256 + t;
    int xx = qid >> 5, c8 = (qid & 31) * 8;
    *(h8_t*)(orow + xx * CC + c8) = *(const h8_t*)(lds + xx * APR_STRIDE + c8);
  }
}

// ---------------- implicit-GEMM conv, 128x128 tile, BK=32, fp16 MFMA ----------------
// Ping-pong LDS double-buffer: loads for chunk t+1 issued before compute of
// chunk t; single barrier per chunk hides most of the staging-load latency.
// SW=false (conv1): D[m][co]; epilogue bn2+relu+gate+quant -> a2out (padded NHWC fp16)
// SW=true  (conv2): D[co][m] via swapped operands; epilogue +residual -> out (NCHW fp32)
template <bool SW>
__global__ __launch_bounds__(256) void k_conv(
    const _Float16* __restrict__ act,   // padded NHWC acts
    const _Float16* __restrict__ wts,   // [9][co][ci] fp16
    const float* __restrict__ stats,
    _Float16* __restrict__ a2out,
    const float* __restrict__ resid,
    float* __restrict__ out) {
  __shared__ __attribute__((aligned(16))) _Float16 As[2][128 * 32];
  __shared__ __attribute__((aligned(16))) _Float16 Ws[2][128 * 32];
  const int tid = threadIdx.x;
  const int lane = tid & 63, wid = tid >> 6;
  const int blk_co = blockIdx.x & 1;
  const int blk_m = blockIdx.x >> 1;

  // ---- staging address precompute (2 rows per thread, XOR seg swizzle)
  const int rr = lane >> 2;
  const int segp = lane & 3;
  const int r0 = wid * 32 + rr;
  const int r1 = r0 + 16;
  const int sg0 = segp ^ ((r0 >> 1) & 3);
  const int sg1 = segp ^ ((r1 >> 1) & 3);
  const int m0 = blk_m * 128 + r0, m1 = blk_m * 128 + r1;
  const int n0 = m0 >> 10, y0 = (m0 >> 5) & 31, x0 = m0 & 31;
  const int n1 = m1 >> 10, y1 = (m1 >> 5) & 31, x1 = m1 & 31;
  const int ab0 = ((n0 * HP + y0) * WP + x0) * CC + sg0 * 8;
  const int ab1 = ((n1 * HP + y1) * WP + x1) * CC + sg1 * 8;
  const int co0 = blk_co * 128 + r0, co1 = blk_co * 128 + r1;
  const int wb0 = co0 * CC + sg0 * 8;
  const int wb1 = co1 * CC + sg1 * 8;

  const int wr = wid >> 1, wc = wid & 1;
  const int ldsA0 = wid * 32 * 32;
  const int ldsA1 = (wid * 32 + 16) * 32;

  f4_t acc[4][4];
  const f4_t z4 = {0.f, 0.f, 0.f, 0.f};
#pragma unroll
  for (int i = 0; i < 4; ++i)
#pragma unroll
    for (int j = 0; j < 4; ++j) acc[i][j] = z4;

  // fragment read offsets (iteration-invariant)
  int raoff[4], rboff[4];
#pragma unroll
  for (int i = 0; i < 4; ++i) {
    int ra = wr * 64 + i * 16 + (lane & 15);
    int sa = (lane >> 4) ^ ((ra >> 1) & 3);
    raoff[i] = ra * 32 + sa * 8;
    int rb = wc * 64 + i * 16 + (lane & 15);
    int sb = (lane >> 4) ^ ((rb >> 1) & 3);
    rboff[i] = rb * 32 + sb * 8;
  }

  auto issue = [&](int t, int b) {
    const int e = t >> 3, kc = t & 7;
    const int kh = (e * 11) >> 5;          // e/3 for e<9
    const int kw = e - 3 * kh;
    const int aoff = (kh * WP + kw) * CC + kc * 32;
    const int woff = e * CC * CC + kc * 32;
    async_load16(&As[b][ldsA0], act + ab0 + aoff);
    async_load16(&As[b][ldsA1], act + ab1 + aoff);
    async_load16(&Ws[b][ldsA0], wts + woff + wb0);
    async_load16(&Ws[b][ldsA1], wts + woff + wb1);
  };

  auto compute = [&](int b) {
    const _Float16* aT = SW ? Ws[b] : As[b];
    const _Float16* bT = SW ? As[b] : Ws[b];
    h8_t fa[4], fb[4];
#pragma unroll
    for (int i = 0; i < 4; ++i) {
      fa[i] = *(const h8_t*)(aT + raoff[i]);
      fb[i] = *(const h8_t*)(bT + rboff[i]);
    }
#pragma unroll
    for (int i = 0; i < 4; ++i)
#pragma unroll
      for (int j = 0; j < 4; ++j)
        acc[i][j] = __builtin_amdgcn_mfma_f32_16x16x32_f16(fa[i], fb[j], acc[i][j], 0, 0, 0);
  };

  issue(0, 0);
  __syncthreads();
#pragma unroll 1
  for (int t = 0; t < 72; t += 2) {
    issue(t + 1, 1);
    compute(0);
    __syncthreads();
    if (t + 2 < 72) issue(t + 2, 0);
    compute(1);
    __syncthreads();
  }

  const int quad = lane >> 4;
  const int cq = lane & 15;
  if (!SW) {
    const float pa0 = stats[S_PA2], pa1 = stats[S_PA2 + 1], pa2 = stats[S_PA2 + 2];
#pragma unroll
    for (int j = 0; j < 4; ++j) {
      const int co = blk_co * 128 + wc * 64 + j * 16 + cq;
      const float sc = stats[S_BN2SC + co];
      const float sh = stats[S_BN2SH + co];
      const float ic = stats[S_INDCH + co];
#pragma unroll
      for (int i = 0; i < 4; ++i) {
        const int mbase = blk_m * 128 + wr * 64 + i * 16 + quad * 4;
#pragma unroll
        for (int rg = 0; rg < 4; ++rg) {
          const int m = mbase + rg;
          const int n = m >> 10, y = (m >> 5) & 31, x = m & 31;
          float h = fmaxf(acc[i][j][rg] * sc + sh, 0.f) * ic;
          float cl = fminf(h, 1.f);
          float q = pa0 * (rintf(cl * 3.f) / 3.f) + pa1 * (rintf(cl * 15.f) / 15.f)
                  + pa2 * (rintf(cl * 255.f) / 255.f);
          a2out[((size_t)(n * HP + y + 1) * WP + (x + 1)) * CC + co] = (_Float16)q;
        }
      }
    }
  } else {
#pragma unroll
    for (int j = 0; j < 4; ++j) {
      const int m = blk_m * 128 + wc * 64 + j * 16 + cq;
      const int n = m >> 10, y = (m >> 5) & 31, x = m & 31;
#pragma unroll
      for (int i = 0; i < 4; ++i) {
        const int cobase = blk_co * 128 + wr * 64 + i * 16 + quad * 4;
#pragma unroll
        for (int rg = 0; rg < 4; ++rg) {
          const int co = cobase + rg;
          const int idx = ((n * CC + co) << 10) + (y << 5) + x;
          out[idx] = acc[i][j][rg] + resid[idx];
        }
      }
    }
  }
}

extern "C" void kernel_launch(void* const* d_in, const int* in_sizes, int n_in,
                              void* d_out, int out_size, void* d_ws, size_t ws_size,
                              hipStream_t stream) {
  const float* x    = (const float*)d_in[0];
  const float* w1   = (const float*)d_in[1];
  const float* w2   = (const float*)d_in[2];
  const float* bn1g = (const float*)d_in[3];
  const float* bn1b = (const float*)d_in[4];
  const float* bn1m = (const float*)d_in[5];
  const float* bn1v = (const float*)d_in[6];
  const float* bn2g = (const float*)d_in[7];
  const float* bn2b = (const float*)d_in[8];
  const float* bn2m = (const float*)d_in[9];
  const float* bn2v = (const float*)d_in[10];
  const float* thr  = (const float*)d_in[11];
  const float* wl1  = (const float*)d_in[12];
  const float* al1  = (const float*)d_in[13];
  const float* wl2  = (const float*)d_in[14];
  const float* al2  = (const float*)d_in[15];

  char* ws = (char*)d_ws;
  float* stats = (float*)(ws + OFF_STATS);
  _Float16* a1 = (_Float16*)(ws + OFF_A1);
  _Float16* a2 = (_Float16*)(ws + OFF_A2);
  _Float16* wt1 = (_Float16*)(ws + OFF_W1T);
  _Float16* wt2 = (_Float16*)(ws + OFF_W2T);
  float* out = (float*)d_out;

  hipMemsetAsync(stats, 0, 8192, stream);
  k_borders<<<2 * BB * 132, 64, 0, stream>>>(a1, a2);
  k_groupstats<<<64, 256, 0, stream>>>(w1, stats);
  k_prep<<<1, 256, 0, stream>>>(thr, bn1g, bn1b, bn1m, bn1v,
                                bn2g, bn2b, bn2m, bn2v, wl1, al1, wl2, al2, stats);
  k_masked<<<512, 256, 0, stream>>>(w1, w2, stats);
  k_final<<<1, 256, 0, stream>>>(stats);
  k_wprep<<<(2 * WELEMS) / 256, 256, 0, stream>>>(w1, w2, stats, wt1, wt2);
  k_aprep<<<BB * HH, 256, 0, stream>>>(x, stats, a1);
  k_conv<false><<<1024, 256, 0, stream>>>(a1, wt1, stats, a2, nullptr, nullptr);
  k_conv<true><<<1024, 256, 0, stream>>>(a2, wt2, stats, nullptr, x, out);
}

// Round 3
// 408.859 us; speedup vs baseline: 1.1138x; 1.1138x over previous
//
#include <hip/hip_runtime.h>
#include <stdint.h>

#define EPSF 1e-5f

typedef _Float16 h8_t __attribute__((ext_vector_type(8)));
typedef float f4_t __attribute__((ext_vector_type(4)));

#define BB 64
#define CC 256
#define HH 32
#define WW 32
#define HP 34
#define WP 34
#define MTOT (BB*HH*WW)        // 65536
#define WELEMS (CC*CC*9)       // 589824
#define PADIMG (HP*WP*CC)      // halfwords per image
#define PADTOT (BB*PADIMG)     // 18939904 halfwords

// ---- stats layout (float offsets)
#define S_MAXABS 0
#define S_GSUM   1     // 64
#define S_SUM1   129
#define S_SQ1    130
#define S_SUM2   131
#define S_SQ2    132
#define S_M1     133
#define S_S1     134
#define S_M2     135
#define S_S2     136
#define S_PW1    137   // 3
#define S_PA1    140   // 3
#define S_PW2    143   // 3
#define S_PA2    146   // 3
#define S_INDCH  160   // 256
#define S_GATE   416   // 256
#define S_BN1SC  672   // 256
#define S_BN1SH  928   // 256
#define S_BN2SC  1184  // 256
#define S_BN2SH  1440  // 256

// ---- ws byte offsets
#define OFF_STATS 0
#define OFF_A1    8192
#define OFF_A2    (OFF_A1 + PADTOT*2)
#define OFF_W1T   (OFF_A2 + PADTOT*2)
#define OFF_W2T   (OFF_W1T + 9*CC*CC*2)

__device__ __forceinline__ void async_load16(void* lds, const void* g) {
  // direct global->LDS, 16B/lane; LDS dest = uniform base + lane*16
  __builtin_amdgcn_global_load_lds(
      reinterpret_cast<uint32_t __attribute__((address_space(1)))*>((uintptr_t)g),
      reinterpret_cast<uint32_t __attribute__((address_space(3)))*>((uint32_t)(uintptr_t)lds),
      16, 0, 0);
}

__device__ __forceinline__ float wave_sum(float v) {
  for (int o = 32; o; o >>= 1) v += __shfl_down(v, o);
  return v;
}
__device__ __forceinline__ float wave_max(float v) {
  for (int o = 32; o; o >>= 1) v = fmaxf(v, __shfl_down(v, o));
  return v;
}

// ---------------- stats: per-group |w1| sums + global maxabs ----------------
__global__ void k_groupstats(const float* __restrict__ w1, float* stats) {
  int g = blockIdx.x;  // 64 groups of 4 out-channels = 9216 contiguous floats
  const float* p = w1 + g * 9216;
  float s = 0.f, mx = 0.f;
  for (int i = threadIdx.x; i < 9216; i += 256) {
    float v = fabsf(p[i]);
    s += v; mx = fmaxf(mx, v);
  }
  s = wave_sum(s); mx = wave_max(mx);
  __shared__ float ls[4], lm[4];
  int lane = threadIdx.x & 63, w = threadIdx.x >> 6;
  if (lane == 0) { ls[w] = s; lm[w] = mx; }
  __syncthreads();
  if (threadIdx.x == 0) {
    float ss = ls[0] + ls[1] + ls[2] + ls[3];
    float mm = fmaxf(fmaxf(lm[0], lm[1]), fmaxf(lm[2], lm[3]));
    stats[S_GSUM + g] = ss;
    atomicMax((unsigned int*)(stats + S_MAXABS), __float_as_uint(mm));
  }
}

__device__ __forceinline__ void softmax3(const float* l, float* out) {
  float m = fmaxf(fmaxf(l[0], l[1]), l[2]);
  float e0 = expf(l[0] - m), e1 = expf(l[1] - m), e2 = expf(l[2] - m);
  float inv = 1.f / (e0 + e1 + e2);
  out[0] = e0 * inv; out[1] = e1 * inv; out[2] = e2 * inv;
}

// ---------------- indicator, gates, bn scale/shift, softmaxes ----------------
__global__ void k_prep(const float* thr_p,
                       const float* bn1g, const float* bn1b, const float* bn1m, const float* bn1v,
                       const float* bn2g, const float* bn2b, const float* bn2m, const float* bn2v,
                       const float* wl1, const float* al1, const float* wl2, const float* al2,
                       float* stats) {
  int t = threadIdx.x;
  float thr = thr_p[0];
  float maxab = stats[S_MAXABS];
  __shared__ float ind[64];
  if (t < 64) {
    float norm = stats[S_GSUM + t] / maxab / 9216.0f;
    float soft = 1.f / (1.f + expf(-(norm - thr)));
    float hard = (norm > thr) ? 1.f : 0.f;
    ind[t] = (hard - soft) + soft;   // STE forward value
  }
  __syncthreads();
  {
    float iv = ind[t >> 2];
    stats[S_INDCH + t] = iv;
    stats[S_GATE + t] = (iv > 0.f) ? 1.f : 0.f;
    float sc1 = bn1g[t] * (1.f / sqrtf(bn1v[t] + EPSF));
    stats[S_BN1SC + t] = sc1;
    stats[S_BN1SH + t] = bn1b[t] - bn1m[t] * sc1;
    float sc2 = bn2g[t] * (1.f / sqrtf(bn2v[t] + EPSF));
    stats[S_BN2SC + t] = sc2;
    stats[S_BN2SH + t] = bn2b[t] - bn2m[t] * sc2;
  }
  if (t == 0) {
    softmax3(wl1, stats + S_PW1);
    softmax3(al1, stats + S_PA1);
    softmax3(wl2, stats + S_PW2);
    softmax3(al2, stats + S_PA2);
  }
}

// ---------------- masked sum / sumsq for w1 (out-ch mask) and w2 (in-ch mask) ----------------
__global__ void k_masked(const float* __restrict__ w1, const float* __restrict__ w2,
                         float* stats) {
  const float* gate = stats + S_GATE;
  float s1 = 0.f, q1 = 0.f, s2 = 0.f, q2 = 0.f;
  for (int i = blockIdx.x * 256 + threadIdx.x; i < 2 * WELEMS; i += gridDim.x * 256) {
    if (i < WELEMS) {
      int o = i / 2304;
      float m = gate[o];
      float v = w1[i];
      s1 += m * v; q1 += m * v * v;
    } else {
      int j = i - WELEMS;
      int ic = (j / 9) & 255;
      float m = gate[ic];
      float v = w2[j];
      s2 += m * v; q2 += m * v * v;
    }
  }
  s1 = wave_sum(s1); q1 = wave_sum(q1); s2 = wave_sum(s2); q2 = wave_sum(q2);
  __shared__ float red[4][4];
  int lane = threadIdx.x & 63, w = threadIdx.x >> 6;
  if (lane == 0) { red[w][0] = s1; red[w][1] = q1; red[w][2] = s2; red[w][3] = q2; }
  __syncthreads();
  if (threadIdx.x == 0) {
    float a = 0, b = 0, c = 0, d = 0;
    for (int k = 0; k < 4; ++k) { a += red[k][0]; b += red[k][1]; c += red[k][2]; d += red[k][3]; }
    atomicAdd(stats + S_SUM1, a); atomicAdd(stats + S_SQ1, b);
    atomicAdd(stats + S_SUM2, c); atomicAdd(stats + S_SQ2, d);
  }
}

// ---------------- finalize masked mean/std (parallel gate-sum) ----------------
__global__ void k_final(float* stats) {
  int t = threadIdx.x;               // 256 threads
  float g = stats[S_GATE + t];
  g = wave_sum(g);
  __shared__ float red[4];
  int lane = t & 63, w = t >> 6;
  if (lane == 0) red[w] = g;
  __syncthreads();
  if (t == 0) {
    float ns = red[0] + red[1] + red[2] + red[3];
    float cnt = ns * 2304.0f;
    float m1 = stats[S_SUM1] / cnt;
    float v1 = (stats[S_SQ1] - cnt * m1 * m1) / (cnt - 1.0f);
    stats[S_M1] = m1; stats[S_S1] = sqrtf(fmaxf(v1, 0.f));
    float m2 = stats[S_SUM2] / cnt;
    float v2 = (stats[S_SQ2] - cnt * m2 * m2) / (cnt - 1.0f);
    stats[S_M2] = m2; stats[S_S2] = sqrtf(fmaxf(v2, 0.f));
  }
}

// ---------------- weight quant+mix -> fp16, layout [e][co][ci] ----------------
__global__ void k_wprep(const float* __restrict__ w1, const float* __restrict__ w2,
                        const float* __restrict__ stats,
                        _Float16* __restrict__ wt1, _Float16* __restrict__ wt2) {
  int t = blockIdx.x * 256 + threadIdx.x;   // 0 .. 2*WELEMS-1
  int which = (t >= WELEMS) ? 1 : 0;
  int r = which ? t - WELEMS : t;
  int e = r >> 16;
  int o = (r >> 8) & 255;
  int ci = r & 255;
  const float* w = which ? w2 : w1;
  float mean = stats[which ? S_M2 : S_M1];
  float sd = stats[which ? S_S2 : S_S1] + EPSF;
  const float* pw = stats + (which ? S_PW2 : S_PW1);
  float v = w[((o << 8) | ci) * 9 + e];
  float wn = fminf(fmaxf((v - mean) / sd, -1.f), 1.f);
  float u0 = rintf((wn + 1.f) * 0.5f * 3.f) / 3.f;
  float u1 = rintf((wn + 1.f) * 0.5f * 15.f) / 15.f;
  float u2 = rintf((wn + 1.f) * 0.5f * 255.f) / 255.f;
  float mix = pw[0] * (2.f * u0 - 1.f) + pw[1] * (2.f * u1 - 1.f) + pw[2] * (2.f * u2 - 1.f);
  (which ? wt2 : wt1)[r] = (_Float16)mix;
}

// ---------------- zero the 1-pixel borders of both padded act buffers ----------------
__global__ void k_borders(_Float16* a1, _Float16* a2) {
  int bid = blockIdx.x;            // 2 * 64 * 132 blocks
  _Float16* base = (bid >= BB * 132) ? a2 : a1;
  int r = (bid >= BB * 132) ? bid - BB * 132 : bid;
  int n = r / 132, b = r % 132;
  int yy, xx;
  if (b < 34)       { yy = 0;       xx = b; }
  else if (b < 68)  { yy = 33;      xx = b - 34; }
  else if (b < 100) { yy = b - 67;  xx = 0; }
  else              { yy = b - 99;  xx = 33; }
  uint64_t* p = (uint64_t*)(base + ((size_t)(n * HP + yy) * WP + xx) * CC);
  p[threadIdx.x] = 0ull;           // 64 threads * 8B = 512B = 256 fp16
}

// ---------------- bn1+relu+quant-mix -> fp16 padded NHWC ----------------
#define APR_STRIDE 264
__global__ void k_aprep(const float* __restrict__ xin, const float* __restrict__ stats,
                        _Float16* __restrict__ a1) {
  __shared__ __attribute__((aligned(16))) _Float16 lds[32 * APR_STRIDE];
  int n = blockIdx.x >> 5, y = blockIdx.x & 31;
  int t = threadIdx.x;
  int x = t & 31, c0 = t >> 5;
  float pa0 = stats[S_PA1], pa1 = stats[S_PA1 + 1], pa2 = stats[S_PA1 + 2];
  const float* bsc = stats + S_BN1SC;
  const float* bsh = stats + S_BN1SH;
  for (int cc = 0; cc < 32; ++cc) {
    int c = cc * 8 + c0;
    float v = xin[((n * CC + c) * HH + y) * WW + x];
    v = fmaxf(v * bsc[c] + bsh[c], 0.f);
    float cl = fminf(v, 1.f);
    float q = pa0 * (rintf(cl * 3.f) / 3.f) + pa1 * (rintf(cl * 15.f) / 15.f)
            + pa2 * (rintf(cl * 255.f) / 255.f);
    lds[x * APR_STRIDE + c] = (_Float16)q;
  }
  __syncthreads();
  _Float16* orow = a1 + ((size_t)(n * HP + (y + 1)) * WP + 1) * CC;
  for (int it = 0; it < 4; ++it) {
    int qid = it * 256 + t;
    int xx = qid >> 5, c8 = (qid & 31) * 8;
    *(h8_t*)(orow + xx * CC + c8) = *(const h8_t*)(lds + xx * APR_STRIDE + c8);
  }
}

// ---------------- implicit-GEMM conv, 128x128 tile, BK=64, fp16 MFMA ----------------
// R1 two-barrier structure (inter-block overlap hides the drain), but 32 MFMA
// + 16 ds_read_b128 per barrier-pair instead of 16+8: per-chunk fixed cost
// (barrier + vmcnt drain) amortized 2x. XOR-swizzle seg^(row&7) gives the
// uniform 8-access/bank floor on the b128 reads (no excess conflicts).
// SW=false (conv1): D[m][co]; epilogue bn2+relu+gate+quant -> a2out (padded NHWC fp16)
// SW=true  (conv2): D[co][m] via swapped operands; epilogue +residual -> out (NCHW fp32)
template <bool SW>
__global__ __launch_bounds__(256) void k_conv(
    const _Float16* __restrict__ act,   // padded NHWC acts
    const _Float16* __restrict__ wts,   // [9][co][ci] fp16
    const float* __restrict__ stats,
    _Float16* __restrict__ a2out,
    const float* __restrict__ resid,
    float* __restrict__ out) {
  __shared__ __attribute__((aligned(16))) _Float16 As[128 * 64];
  __shared__ __attribute__((aligned(16))) _Float16 Ws[128 * 64];
  const int tid = threadIdx.x;
  const int lane = tid & 63, wid = tid >> 6;
  const int blk_co = blockIdx.x & 1;
  const int blk_m = blockIdx.x >> 1;

  // ---- staging: 4 issues per tile; issue q covers rows q*32 + wid*8 + (lane>>3).
  // LDS seg s = lane&7 holds global seg g = s ^ (row&7); row&7 == lane>>3.
  const int srow = wid * 8 + (lane >> 3);
  const int g = (lane & 7) ^ (lane >> 3);
  int abase[4], wbase[4];
#pragma unroll
  for (int q = 0; q < 4; ++q) {
    int r = q * 32 + srow;
    int m = blk_m * 128 + r;
    int n = m >> 10, y = (m >> 5) & 31, x = m & 31;
    abase[q] = ((n * HP + y) * WP + x) * CC + g * 8;
    wbase[q] = (blk_co * 128 + r) * CC + g * 8;
  }

  const int wr = wid >> 1, wc = wid & 1;

  f4_t acc[4][4];
  const f4_t z4 = {0.f, 0.f, 0.f, 0.f};
#pragma unroll
  for (int i = 0; i < 4; ++i)
#pragma unroll
    for (int j = 0; j < 4; ++j) acc[i][j] = z4;

  // fragment read offsets (iteration-invariant). kk=1 offset = kk=0 offset ^ 32.
  int raoff[4], rboff[4];
#pragma unroll
  for (int i = 0; i < 4; ++i) {
    int ra = wr * 64 + i * 16 + (lane & 15);
    int sa = (lane >> 4) ^ (lane & 7);
    raoff[i] = ra * 64 + sa * 8;
    int rb = wc * 64 + i * 16 + (lane & 15);
    rboff[i] = rb * 64 + sa * 8;
  }

#pragma unroll 1
  for (int e = 0; e < 9; ++e) {
    const int kh = e / 3, kw = e - 3 * kh;
    const int aoffe = (kh * WP + kw) * CC;
    const int woffe = e * CC * CC;
#pragma unroll
    for (int kc = 0; kc < 4; ++kc) {
      const int ao = aoffe + kc * 64;
      const int wo = woffe + kc * 64;
      __syncthreads();
#pragma unroll
      for (int q = 0; q < 4; ++q) {
        async_load16(As + (q * 32 + wid * 8) * 64, act + abase[q] + ao);
        async_load16(Ws + (q * 32 + wid * 8) * 64, wts + wbase[q] + wo);
      }
      __syncthreads();
      const _Float16* aT = SW ? Ws : As;
      const _Float16* bT = SW ? As : Ws;
#pragma unroll
      for (int kk = 0; kk < 2; ++kk) {
        h8_t fa[4], fb[4];
#pragma unroll
        for (int i = 0; i < 4; ++i) {
          fa[i] = *(const h8_t*)(aT + (raoff[i] ^ (kk * 32)));
          fb[i] = *(const h8_t*)(bT + (rboff[i] ^ (kk * 32)));
        }
#pragma unroll
        for (int i = 0; i < 4; ++i)
#pragma unroll
          for (int j = 0; j < 4; ++j)
            acc[i][j] = __builtin_amdgcn_mfma_f32_16x16x32_f16(fa[i], fb[j], acc[i][j], 0, 0, 0);
      }
    }
  }

  const int quad = lane >> 4;
  const int cq = lane & 15;
  if (!SW) {
    const float pa0 = stats[S_PA2], pa1 = stats[S_PA2 + 1], pa2 = stats[S_PA2 + 2];
#pragma unroll
    for (int j = 0; j < 4; ++j) {
      const int co = blk_co * 128 + wc * 64 + j * 16 + cq;
      const float sc = stats[S_BN2SC + co];
      const float sh = stats[S_BN2SH + co];
      const float ic = stats[S_INDCH + co];
#pragma unroll
      for (int i = 0; i < 4; ++i) {
        const int mbase = blk_m * 128 + wr * 64 + i * 16 + quad * 4;
#pragma unroll
        for (int rg = 0; rg < 4; ++rg) {
          const int m = mbase + rg;
          const int n = m >> 10, y = (m >> 5) & 31, x = m & 31;
          float h = fmaxf(acc[i][j][rg] * sc + sh, 0.f) * ic;
          float cl = fminf(h, 1.f);
          float q = pa0 * (rintf(cl * 3.f) / 3.f) + pa1 * (rintf(cl * 15.f) / 15.f)
                  + pa2 * (rintf(cl * 255.f) / 255.f);
          a2out[((size_t)(n * HP + y + 1) * WP + (x + 1)) * CC + co] = (_Float16)q;
        }
      }
    }
  } else {
#pragma unroll
    for (int j = 0; j < 4; ++j) {
      const int m = blk_m * 128 + wc * 64 + j * 16 + cq;
      const int n = m >> 10, y = (m >> 5) & 31, x = m & 31;
#pragma unroll
      for (int i = 0; i < 4; ++i) {
        const int cobase = blk_co * 128 + wr * 64 + i * 16 + quad * 4;
#pragma unroll
        for (int rg = 0; rg < 4; ++rg) {
          const int co = cobase + rg;
          const int idx = ((n * CC + co) << 10) + (y << 5) + x;
          out[idx] = acc[i][j][rg] + resid[idx];
        }
      }
    }
  }
}

extern "C" void kernel_launch(void* const* d_in, const int* in_sizes, int n_in,
                              void* d_out, int out_size, void* d_ws, size_t ws_size,
                              hipStream_t stream) {
  const float* x    = (const float*)d_in[0];
  const float* w1   = (const float*)d_in[1];
  const float* w2   = (const float*)d_in[2];
  const float* bn1g = (const float*)d_in[3];
  const float* bn1b = (const float*)d_in[4];
  const float* bn1m = (const float*)d_in[5];
  const float* bn1v = (const float*)d_in[6];
  const float* bn2g = (const float*)d_in[7];
  const float* bn2b = (const float*)d_in[8];
  const float* bn2m = (const float*)d_in[9];
  const float* bn2v = (const float*)d_in[10];
  const float* thr  = (const float*)d_in[11];
  const float* wl1  = (const float*)d_in[12];
  const float* al1  = (const float*)d_in[13];
  const float* wl2  = (const float*)d_in[14];
  const float* al2  = (const float*)d_in[15];

  char* ws = (char*)d_ws;
  float* stats = (float*)(ws + OFF_STATS);
  _Float16* a1 = (_Float16*)(ws + OFF_A1);
  _Float16* a2 = (_Float16*)(ws + OFF_A2);
  _Float16* wt1 = (_Float16*)(ws + OFF_W1T);
  _Float16* wt2 = (_Float16*)(ws + OFF_W2T);
  float* out = (float*)d_out;

  hipMemsetAsync(stats, 0, 8192, stream);
  k_borders<<<2 * BB * 132, 64, 0, stream>>>(a1, a2);
  k_groupstats<<<64, 256, 0, stream>>>(w1, stats);
  k_prep<<<1, 256, 0, stream>>>(thr, bn1g, bn1b, bn1m, bn1v,
                                bn2g, bn2b, bn2m, bn2v, wl1, al1, wl2, al2, stats);
  k_masked<<<512, 256, 0, stream>>>(w1, w2, stats);
  k_final<<<1, 256, 0, stream>>>(stats);
  k_wprep<<<(2 * WELEMS) / 256, 256, 0, stream>>>(w1, w2, stats, wt1, wt2);
  k_aprep<<<BB * HH, 256, 0, stream>>>(x, stats, a1);
  k_conv<false><<<1024, 256, 0, stream>>>(a1, wt1, stats, a2, nullptr, nullptr);
  k_conv<true><<<1024, 256, 0, stream>>>(a2, wt2, stats, nullptr, x, out);
}

// Round 5
// 363.805 us; speedup vs baseline: 1.2517x; 1.1238x over previous
//
#include <hip/hip_runtime.h>
#include <stdint.h>

#define EPSF 1e-5f

typedef _Float16 h8_t __attribute__((ext_vector_type(8)));
typedef float f4_t __attribute__((ext_vector_type(4)));

#define BB 64
#define CC 256
#define HH 32
#define WW 32
#define HP 34
#define WP 34
#define MTOT (BB*HH*WW)        // 65536
#define WELEMS (CC*CC*9)       // 589824
#define PADIMG (HP*WP*CC)      // halfwords per image
#define PADTOT (BB*PADIMG)     // 18939904 halfwords

// ---- stats layout (float offsets); every slot written every launch (no memset)
#define S_GSUM   0     // 64: per-group sum |w1|
#define S_GMAX   64    // 64: per-group max |w1|
#define S_W1S    128   // 64: per-group sum w1
#define S_W1Q    192   // 64: per-group sum w1^2
#define S_W2S    256   // 64: per-in-group sum w2
#define S_W2Q    320   // 64
#define S_M1     384
#define S_SD1    385
#define S_M2     386
#define S_SD2    387
#define S_PW1    388   // 3
#define S_PA1    391   // 3
#define S_PW2    394   // 3
#define S_PA2    397   // 3
#define S_INDCH  400   // 256
#define S_BN1SC  656   // 256
#define S_BN1SH  912   // 256
#define S_BN2SC  1168  // 256
#define S_BN2SH  1424  // 256

// ---- ws byte offsets
#define OFF_STATS 0
#define OFF_A1    8192
#define OFF_A2    (OFF_A1 + PADTOT*2)
#define OFF_W1T   (OFF_A2 + PADTOT*2)
#define OFF_W2T   (OFF_W1T + 9*CC*CC*2)

__device__ __forceinline__ void async_load16(void* lds, const void* g) {
  // direct global->LDS, 16B/lane; LDS dest = uniform base + lane*16
  __builtin_amdgcn_global_load_lds(
      reinterpret_cast<uint32_t __attribute__((address_space(1)))*>((uintptr_t)g),
      reinterpret_cast<uint32_t __attribute__((address_space(3)))*>((uint32_t)(uintptr_t)lds),
      16, 0, 0);
}

__device__ __forceinline__ float wave_sum(float v) {
  for (int o = 32; o; o >>= 1) v += __shfl_down(v, o);
  return v;
}
__device__ __forceinline__ float wave_max(float v) {
  for (int o = 32; o; o >>= 1) v = fmaxf(v, __shfl_down(v, o));
  return v;
}

__device__ __forceinline__ void softmax3(const float* l, float* out) {
  float m = fmaxf(fmaxf(l[0], l[1]), l[2]);
  float e0 = expf(l[0] - m), e1 = expf(l[1] - m), e2 = expf(l[2] - m);
  float inv = 1.f / (e0 + e1 + e2);
  out[0] = e0 * inv; out[1] = e1 * inv; out[2] = e2 * inv;
}

// ---------------- fused per-group stats: one pass over w1 and w2 ----------------
// blocks 0..63  : w1 out-group g -> sum|w|, max|w|, sum w, sum w^2 (contiguous 9216 floats)
// blocks 64..127: w2 in-group g  -> sum w, sum w^2 (per o: 36 contiguous floats)
__global__ void k_stats(const float* __restrict__ w1, const float* __restrict__ w2,
                        float* stats) {
  __shared__ float red[4][4];
  int bid = blockIdx.x, t = threadIdx.x;
  int lane = t & 63, w = t >> 6;
  if (bid < 64) {
    const float* p = w1 + bid * 9216;
    float sa = 0.f, s = 0.f, q = 0.f, mx = 0.f;
    for (int i = t; i < 9216; i += 256) {
      float v = p[i];
      float a = fabsf(v);
      sa += a; s += v; q += v * v; mx = fmaxf(mx, a);
    }
    sa = wave_sum(sa); s = wave_sum(s); q = wave_sum(q); mx = wave_max(mx);
    if (lane == 0) { red[w][0] = sa; red[w][1] = s; red[w][2] = q; red[w][3] = mx; }
    __syncthreads();
    if (t == 0) {
      float a = 0, b = 0, c = 0, d = 0;
      for (int k = 0; k < 4; ++k) {
        a += red[k][0]; b += red[k][1]; c += red[k][2]; d = fmaxf(d, red[k][3]);
      }
      stats[S_GSUM + bid] = a;
      stats[S_W1S + bid] = b;
      stats[S_W1Q + bid] = c;
      stats[S_GMAX + bid] = d;
    }
  } else {
    int g = bid - 64;
    const float* p = w2 + (size_t)t * 2304 + g * 36;  // o = t, ic in [4g,4g+4)
    float s = 0.f, q = 0.f;
#pragma unroll
    for (int i = 0; i < 36; ++i) { float v = p[i]; s += v; q += v * v; }
    s = wave_sum(s); q = wave_sum(q);
    if (lane == 0) { red[w][0] = s; red[w][1] = q; }
    __syncthreads();
    if (t == 0) {
      float a = 0, b = 0;
      for (int k = 0; k < 4; ++k) { a += red[k][0]; b += red[k][1]; }
      stats[S_W2S + g] = a;
      stats[S_W2Q + g] = b;
    }
  }
}

// ---------------- indicator, gates, masked mean/std, bn consts, softmaxes ----------------
__global__ void k_prep2(const float* thr_p,
                        const float* bn1g, const float* bn1b, const float* bn1m, const float* bn1v,
                        const float* bn2g, const float* bn2b, const float* bn2m, const float* bn2v,
                        const float* wl1, const float* al1, const float* wl2, const float* al2,
                        float* stats) {
  int t = threadIdx.x;
  __shared__ float sind[64];
  if (t < 64) {
    float thr = thr_p[0];
    float mx = wave_max(stats[S_GMAX + t]);
    mx = __shfl(mx, 0);
    float norm = stats[S_GSUM + t] / mx / 9216.0f;
    float soft = 1.f / (1.f + expf(-(norm - thr)));
    float hard = (norm > thr) ? 1.f : 0.f;
    float iv = (hard - soft) + soft;   // STE forward value
    sind[t] = iv;
    float gate = (iv > 0.f) ? 1.f : 0.f;
    float ng = wave_sum(gate);                       // gated groups
    float s1 = wave_sum(gate * stats[S_W1S + t]);
    float q1 = wave_sum(gate * stats[S_W1Q + t]);
    float s2 = wave_sum(gate * stats[S_W2S + t]);
    float q2 = wave_sum(gate * stats[S_W2Q + t]);
    if (t == 0) {
      float cnt = ng * 4.0f * 2304.0f;
      float m1 = s1 / cnt;
      float v1 = (q1 - cnt * m1 * m1) / (cnt - 1.0f);
      stats[S_M1] = m1; stats[S_SD1] = sqrtf(fmaxf(v1, 0.f));
      float m2 = s2 / cnt;
      float v2 = (q2 - cnt * m2 * m2) / (cnt - 1.0f);
      stats[S_M2] = m2; stats[S_SD2] = sqrtf(fmaxf(v2, 0.f));
      softmax3(wl1, stats + S_PW1);
      softmax3(al1, stats + S_PA1);
      softmax3(wl2, stats + S_PW2);
      softmax3(al2, stats + S_PA2);
    }
  }
  __syncthreads();
  stats[S_INDCH + t] = sind[t >> 2];
  float sc1 = bn1g[t] * (1.f / sqrtf(bn1v[t] + EPSF));
  stats[S_BN1SC + t] = sc1;
  stats[S_BN1SH + t] = bn1b[t] - bn1m[t] * sc1;
  float sc2 = bn2g[t] * (1.f / sqrtf(bn2v[t] + EPSF));
  stats[S_BN2SC + t] = sc2;
  stats[S_BN2SH + t] = bn2b[t] - bn2m[t] * sc2;
}

// ---------------- weight quant+mix -> fp16 [e][co][ci], coalesced via LDS ----------------
#define WPS 264   // LDS row stride (halfwords) per e-plane; 528B, 16B-aligned
__global__ void k_wprep(const float* __restrict__ w1, const float* __restrict__ w2,
                        const float* __restrict__ stats,
                        _Float16* __restrict__ wt1, _Float16* __restrict__ wt2) {
  __shared__ __attribute__((aligned(16))) _Float16 lds[9 * WPS];
  int bid = blockIdx.x;
  int which = bid >> 8, o = bid & 255;
  const float* w = (which ? w2 : w1) + (size_t)o * 2304;
  float mean = stats[which ? S_M2 : S_M1];
  float sd = stats[which ? S_SD2 : S_SD1] + EPSF;
  const float* pw = stats + (which ? S_PW2 : S_PW1);
  float p0 = pw[0], p1 = pw[1], p2 = pw[2];
  int t = threadIdx.x;
#pragma unroll
  for (int it = 0; it < 9; ++it) {
    int f = it * 256 + t;          // f = ci*9 + e
    float v = w[f];
    float wn = fminf(fmaxf((v - mean) / sd, -1.f), 1.f);
    float u0 = rintf((wn + 1.f) * 0.5f * 3.f) / 3.f;
    float u1 = rintf((wn + 1.f) * 0.5f * 15.f) / 15.f;
    float u2 = rintf((wn + 1.f) * 0.5f * 255.f) / 255.f;
    float mix = p0 * (2.f * u0 - 1.f) + p1 * (2.f * u1 - 1.f) + p2 * (2.f * u2 - 1.f);
    int ci = f / 9;
    int e = f - 9 * ci;
    lds[e * WPS + ci] = (_Float16)mix;
  }
  __syncthreads();
  _Float16* dst0 = (which ? wt2 : wt1) + o * 256;
#pragma unroll
  for (int it = 0; it < 2; ++it) {
    int qid = it * 256 + t;
    if (qid < 288) {
      int e = qid >> 5, c8 = (qid & 31) * 8;
      *(h8_t*)(dst0 + e * 65536 + c8) = *(const h8_t*)(lds + e * WPS + c8);
    }
  }
}

// ---------------- bn1+relu+quant-mix -> fp16 padded NHWC; +border zeroing ----------------
#define APR_STRIDE 264
__global__ void k_aprep(const float* __restrict__ xin, const float* __restrict__ stats,
                        _Float16* __restrict__ a1, _Float16* __restrict__ a2) {
  __shared__ __attribute__((aligned(16))) _Float16 lds[32 * APR_STRIDE];
  int bid = blockIdx.x;
  int t = threadIdx.x;
  if (bid >= BB * HH) {
    // border blocks: zero the 1-pixel frame of one padded image
    int b = bid - BB * HH;            // 0..127
    _Float16* img = (b >= BB ? a2 : a1) + (size_t)(b & 63) * PADIMG;
    uint64_t* u = (uint64_t*)img;
    // rows 0 and 33: 2176 u64 each (full rows, all channels)
#pragma unroll
    for (int it = 0; it < 17; ++it) {
      int idx = it * 256 + t;          // 0..4351
      int r33 = (idx >= 2176);
      u[(size_t)(r33 ? 33 * WP * 64 : 0) + (idx - (r33 ? 2176 : 0))] = 0ull;
    }
    // cols 0/33 of rows 1..32: 64 pixels x 64 u64 (512B = 256 fp16) = 4096 u64
#pragma unroll
    for (int it = 0; it < 16; ++it) {
      int idx = it * 256 + t;          // 0..4095
      int p = idx >> 6;                // pixel 0..63
      int y = 1 + (p >> 1), x = (p & 1) ? 33 : 0;
      u[(size_t)(y * WP + x) * 64 + (idx & 63)] = 0ull;
    }
    return;
  }
  int n = bid >> 5, y = bid & 31;
  int x4 = (t & 7) * 4, c0 = t >> 3;   // c0 = 0..31
  float pa0 = stats[S_PA1], pa1 = stats[S_PA1 + 1], pa2 = stats[S_PA1 + 2];
  const float* bsc = stats + S_BN1SC;
  const float* bsh = stats + S_BN1SH;
#pragma unroll
  for (int it = 0; it < 8; ++it) {
    int c = it * 32 + c0;
    const float* src = xin + ((size_t)(n * CC + c) * HH + y) * WW + x4;
    float4 v = *(const float4*)src;
    float sc = bsc[c], sh = bsh[c];
#pragma unroll
    for (int k = 0; k < 4; ++k) {
      float vv = (&v.x)[k];
      vv = fmaxf(vv * sc + sh, 0.f);
      float cl = fminf(vv, 1.f);
      float q = pa0 * (rintf(cl * 3.f) / 3.f) + pa1 * (rintf(cl * 15.f) / 15.f)
              + pa2 * (rintf(cl * 255.f) / 255.f);
      lds[(x4 + k) * APR_STRIDE + c] = (_Float16)q;
    }
  }
  __syncthreads();
  _Float16* orow = a1 + ((size_t)(n * HP + (y + 1)) * WP + 1) * CC;
#pragma unroll
  for (int it = 0; it < 4; ++it) {
    int qid = it * 256 + t;
    int xx = qid >> 5, c8 = (qid & 31) * 8;
    *(h8_t*)(orow + xx * CC + c8) = *(const h8_t*)(lds + xx * APR_STRIDE + c8);
  }
}

// ---------------- implicit-GEMM conv, 128x128 tile, BK=64, fp16 MFMA ----------------
// Two-barrier K-loop (R3 structure) + XCD-aware block swizzle: XCD k owns
// m-tiles [64k,64k+64) (8 images, ~4.7MB act slice) for both co halves ->
// act/weight staging served mostly from the XCD-local L2.
// SW=false (conv1): D[m][co]; epilogue bn2+relu+gate+quant -> a2out (padded NHWC fp16)
// SW=true  (conv2): D[co][m] via swapped operands; epilogue +residual -> out (NCHW fp32)
template <bool SW>
__global__ __launch_bounds__(256) void k_conv(
    const _Float16* __restrict__ act,   // padded NHWC acts
    const _Float16* __restrict__ wts,   // [9][co][ci] fp16
    const float* __restrict__ stats,
    _Float16* __restrict__ a2out,
    const float* __restrict__ resid,
    float* __restrict__ out) {
  __shared__ __attribute__((aligned(16))) _Float16 As[128 * 64];
  __shared__ __attribute__((aligned(16))) _Float16 Ws[128 * 64];
  const int tid = threadIdx.x;
  const int lane = tid & 63, wid = tid >> 6;
  // XCD swizzle: blockIdx%8 = XCD; give each XCD 64 contiguous m-tiles x 2 co
  const int xcd = blockIdx.x & 7;
  const int j = blockIdx.x >> 3;          // 0..127
  const int blk_co = j >> 6;
  const int blk_m = xcd * 64 + (j & 63);

  // ---- staging: 4 issues per tile; issue q covers rows q*32 + wid*8 + (lane>>3).
  // LDS seg s = lane&7 holds global seg g = s ^ (row&7); row&7 == lane>>3.
  const int srow = wid * 8 + (lane >> 3);
  const int g = (lane & 7) ^ (lane >> 3);
  int abase[4], wbase[4];
#pragma unroll
  for (int q = 0; q < 4; ++q) {
    int r = q * 32 + srow;
    int m = blk_m * 128 + r;
    int n = m >> 10, y = (m >> 5) & 31, x = m & 31;
    abase[q] = ((n * HP + y) * WP + x) * CC + g * 8;
    wbase[q] = (blk_co * 128 + r) * CC + g * 8;
  }

  const int wr = wid >> 1, wc = wid & 1;

  f4_t acc[4][4];
  const f4_t z4 = {0.f, 0.f, 0.f, 0.f};
#pragma unroll
  for (int i = 0; i < 4; ++i)
#pragma unroll
    for (int j2 = 0; j2 < 4; ++j2) acc[i][j2] = z4;

  // fragment read offsets (iteration-invariant). kk=1 offset = kk=0 offset ^ 32.
  int raoff[4], rboff[4];
#pragma unroll
  for (int i = 0; i < 4; ++i) {
    int ra = wr * 64 + i * 16 + (lane & 15);
    int sa = (lane >> 4) ^ (lane & 7);
    raoff[i] = ra * 64 + sa * 8;
    int rb = wc * 64 + i * 16 + (lane & 15);
    rboff[i] = rb * 64 + sa * 8;
  }

#pragma unroll 1
  for (int e = 0; e < 9; ++e) {
    const int kh = e / 3, kw = e - 3 * kh;
    const int aoffe = (kh * WP + kw) * CC;
    const int woffe = e * CC * CC;
#pragma unroll
    for (int kc = 0; kc < 4; ++kc) {
      const int ao = aoffe + kc * 64;
      const int wo = woffe + kc * 64;
      __syncthreads();
#pragma unroll
      for (int q = 0; q < 4; ++q) {
        async_load16(As + (q * 32 + wid * 8) * 64, act + abase[q] + ao);
        async_load16(Ws + (q * 32 + wid * 8) * 64, wts + wbase[q] + wo);
      }
      __syncthreads();
      const _Float16* aT = SW ? Ws : As;
      const _Float16* bT = SW ? As : Ws;
#pragma unroll
      for (int kk = 0; kk < 2; ++kk) {
        h8_t fa[4], fb[4];
#pragma unroll
        for (int i = 0; i < 4; ++i) {
          fa[i] = *(const h8_t*)(aT + (raoff[i] ^ (kk * 32)));
          fb[i] = *(const h8_t*)(bT + (rboff[i] ^ (kk * 32)));
        }
#pragma unroll
        for (int i = 0; i < 4; ++i)
#pragma unroll
          for (int j2 = 0; j2 < 4; ++j2)
            acc[i][j2] = __builtin_amdgcn_mfma_f32_16x16x32_f16(fa[i], fb[j2], acc[i][j2], 0, 0, 0);
      }
    }
  }

  const int quad = lane >> 4;
  const int cq = lane & 15;
  if (!SW) {
    const float pa0 = stats[S_PA2], pa1 = stats[S_PA2 + 1], pa2 = stats[S_PA2 + 2];
#pragma unroll
    for (int j2 = 0; j2 < 4; ++j2) {
      const int co = blk_co * 128 + wc * 64 + j2 * 16 + cq;
      const float sc = stats[S_BN2SC + co];
      const float sh = stats[S_BN2SH + co];
      const float ic = stats[S_INDCH + co];
#pragma unroll
      for (int i = 0; i < 4; ++i) {
        const int mbase = blk_m * 128 + wr * 64 + i * 16 + quad * 4;
#pragma unroll
        for (int rg = 0; rg < 4; ++rg) {
          const int m = mbase + rg;
          const int n = m >> 10, y = (m >> 5) & 31, x = m & 31;
          float h = fmaxf(acc[i][j2][rg] * sc + sh, 0.f) * ic;
          float cl = fminf(h, 1.f);
          float q = pa0 * (rintf(cl * 3.f) / 3.f) + pa1 * (rintf(cl * 15.f) / 15.f)
                  + pa2 * (rintf(cl * 255.f) / 255.f);
          a2out[((size_t)(n * HP + y + 1) * WP + (x + 1)) * CC + co] = (_Float16)q;
        }
      }
    }
  } else {
#pragma unroll
    for (int j2 = 0; j2 < 4; ++j2) {
      const int m = blk_m * 128 + wc * 64 + j2 * 16 + cq;
      const int n = m >> 10, y = (m >> 5) & 31, x = m & 31;
#pragma unroll
      for (int i = 0; i < 4; ++i) {
        const int cobase = blk_co * 128 + wr * 64 + i * 16 + quad * 4;
#pragma unroll
        for (int rg = 0; rg < 4; ++rg) {
          const int co = cobase + rg;
          const int idx = ((n * CC + co) << 10) + (y << 5) + x;
          out[idx] = acc[i][j2][rg] + resid[idx];
        }
      }
    }
  }
}

extern "C" void kernel_launch(void* const* d_in, const int* in_sizes, int n_in,
                              void* d_out, int out_size, void* d_ws, size_t ws_size,
                              hipStream_t stream) {
  const float* x    = (const float*)d_in[0];
  const float* w1   = (const float*)d_in[1];
  const float* w2   = (const float*)d_in[2];
  const float* bn1g = (const float*)d_in[3];
  const float* bn1b = (const float*)d_in[4];
  const float* bn1m = (const float*)d_in[5];
  const float* bn1v = (const float*)d_in[6];
  const float* bn2g = (const float*)d_in[7];
  const float* bn2b = (const float*)d_in[8];
  const float* bn2m = (const float*)d_in[9];
  const float* bn2v = (const float*)d_in[10];
  const float* thr  = (const float*)d_in[11];
  const float* wl1  = (const float*)d_in[12];
  const float* al1  = (const float*)d_in[13];
  const float* wl2  = (const float*)d_in[14];
  const float* al2  = (const float*)d_in[15];

  char* ws = (char*)d_ws;
  float* stats = (float*)(ws + OFF_STATS);
  _Float16* a1 = (_Float16*)(ws + OFF_A1);
  _Float16* a2 = (_Float16*)(ws + OFF_A2);
  _Float16* wt1 = (_Float16*)(ws + OFF_W1T);
  _Float16* wt2 = (_Float16*)(ws + OFF_W2T);
  float* out = (float*)d_out;

  k_stats<<<128, 256, 0, stream>>>(w1, w2, stats);
  k_prep2<<<1, 256, 0, stream>>>(thr, bn1g, bn1b, bn1m, bn1v,
                                 bn2g, bn2b, bn2m, bn2v, wl1, al1, wl2, al2, stats);
  k_wprep<<<512, 256, 0, stream>>>(w1, w2, stats, wt1, wt2);
  k_aprep<<<BB * HH + 128, 256, 0, stream>>>(x, stats, a1, a2);
  k_conv<false><<<1024, 256, 0, stream>>>(a1, wt1, stats, a2, nullptr, nullptr);
  k_conv<true><<<1024, 256, 0, stream>>>(a2, wt2, stats, nullptr, x, out);
}

// Round 6
// 340.920 us; speedup vs baseline: 1.3357x; 1.0671x over previous
//
#include <hip/hip_runtime.h>
#include <stdint.h>

#define EPSF 1e-5f

typedef _Float16 h8_t __attribute__((ext_vector_type(8)));
typedef float f4_t __attribute__((ext_vector_type(4)));

#define BB 64
#define CC 256
#define HH 32
#define WW 32
#define HP 34
#define WP 34
#define PADIMG (HP*WP*CC)      // halfwords per image
#define PADTOT (BB*PADIMG)

// ---- stats layout (float offsets); every slot written every launch
#define S_GSUM   0     // 64: per-group sum |w1|
#define S_GMAX   64    // 64: per-group max |w1|
#define S_W1S    128   // 64
#define S_W1Q    192   // 64
#define S_W2S    256   // 64
#define S_W2Q    320   // 64
#define S_PA2    384   // 3 (written by fused block 0, read by conv1)
#define S_INDCH  400   // 256
#define S_BN2SC  656   // 256
#define S_BN2SH  912   // 256

// ---- ws byte offsets
#define OFF_STATS 0
#define OFF_A1    8192
#define OFF_A2    (OFF_A1 + PADTOT*2)
#define OFF_W1T   (OFF_A2 + PADTOT*2)
#define OFF_W2T   (OFF_W1T + 9*CC*CC*2)

__device__ __forceinline__ void async_load16(void* lds, const void* g) {
  __builtin_amdgcn_global_load_lds(
      reinterpret_cast<uint32_t __attribute__((address_space(1)))*>((uintptr_t)g),
      reinterpret_cast<uint32_t __attribute__((address_space(3)))*>((uint32_t)(uintptr_t)lds),
      16, 0, 0);
}

__device__ __forceinline__ float wave_sum(float v) {
  for (int o = 32; o; o >>= 1) v += __shfl_down(v, o);
  return v;
}
__device__ __forceinline__ float wave_max(float v) {
  for (int o = 32; o; o >>= 1) v = fmaxf(v, __shfl_down(v, o));
  return v;
}

__device__ __forceinline__ void softmax3(const float* l, float* out) {
  float m = fmaxf(fmaxf(l[0], l[1]), l[2]);
  float e0 = expf(l[0] - m), e1 = expf(l[1] - m), e2 = expf(l[2] - m);
  float inv = 1.f / (e0 + e1 + e2);
  out[0] = e0 * inv; out[1] = e1 * inv; out[2] = e2 * inv;
}

// quant-mix helper (activations): clip[0,1] then 2/4/8-bit STE mix
__device__ __forceinline__ float qmix_act(float v, float p0, float p1, float p2) {
  float cl = fminf(fmaxf(v, 0.f), 1.f);
  return p0 * (rintf(cl * 3.f) / 3.f) + p1 * (rintf(cl * 15.f) / 15.f)
       + p2 * (rintf(cl * 255.f) / 255.f);
}

// ---------------- per-group stats: one pass over w1 and w2 ----------------
__global__ void k_stats(const float* __restrict__ w1, const float* __restrict__ w2,
                        float* stats) {
  __shared__ float red[4][4];
  int bid = blockIdx.x, t = threadIdx.x;
  int lane = t & 63, w = t >> 6;
  if (bid < 64) {
    const float* p = w1 + bid * 9216;
    float sa = 0.f, s = 0.f, q = 0.f, mx = 0.f;
    for (int i = t; i < 9216; i += 256) {
      float v = p[i];
      float a = fabsf(v);
      sa += a; s += v; q += v * v; mx = fmaxf(mx, a);
    }
    sa = wave_sum(sa); s = wave_sum(s); q = wave_sum(q); mx = wave_max(mx);
    if (lane == 0) { red[w][0] = sa; red[w][1] = s; red[w][2] = q; red[w][3] = mx; }
    __syncthreads();
    if (t == 0) {
      float a = 0, b = 0, c = 0, d = 0;
      for (int k = 0; k < 4; ++k) {
        a += red[k][0]; b += red[k][1]; c += red[k][2]; d = fmaxf(d, red[k][3]);
      }
      stats[S_GSUM + bid] = a;
      stats[S_W1S + bid] = b;
      stats[S_W1Q + bid] = c;
      stats[S_GMAX + bid] = d;
    }
  } else {
    int g = bid - 64;
    const float* p = w2 + (size_t)t * 2304 + g * 36;
    float s = 0.f, q = 0.f;
#pragma unroll
    for (int i = 0; i < 36; ++i) { float v = p[i]; s += v; q += v * v; }
    s = wave_sum(s); q = wave_sum(q);
    if (lane == 0) { red[w][0] = s; red[w][1] = q; }
    __syncthreads();
    if (t == 0) {
      float a = 0, b = 0;
      for (int k = 0; k < 4; ++k) { a += red[k][0]; b += red[k][1]; }
      stats[S_W2S + g] = a;
      stats[S_W2Q + g] = b;
    }
  }
}

// ---------------- fused prep + wprep + aprep (+ borders) ----------------
// block 0          : conv1 epilogue consts (indicator, bn2, pa2)
// blocks 1..512    : weight quant+mix -> fp16 [e][co][ci] (inline gate reduce)
// blocks 513..2560 : bn1+relu+qmix act -> fp16 padded NHWC (inline bn1/pa1)
// blocks 2561..2688: border zeroing
#define WPS 264
#define APR_STRIDE 264
__global__ void k_fused(const float* __restrict__ w1, const float* __restrict__ w2,
                        const float* __restrict__ xin, const float* __restrict__ thr_p,
                        const float* __restrict__ bn1g, const float* __restrict__ bn1b,
                        const float* __restrict__ bn1m, const float* __restrict__ bn1v,
                        const float* __restrict__ bn2g, const float* __restrict__ bn2b,
                        const float* __restrict__ bn2m, const float* __restrict__ bn2v,
                        const float* __restrict__ wl1, const float* __restrict__ al1,
                        const float* __restrict__ wl2, const float* __restrict__ al2,
                        float* __restrict__ stats,
                        _Float16* __restrict__ wt1, _Float16* __restrict__ wt2,
                        _Float16* __restrict__ a1, _Float16* __restrict__ a2) {
  int bid = blockIdx.x, t = threadIdx.x;

  if (bid == 0) {
    __shared__ float sind[64];
    if (t < 64) {
      float thr = thr_p[0];
      float mx = wave_max(stats[S_GMAX + t]);
      mx = __shfl(mx, 0);
      float norm = stats[S_GSUM + t] / mx / 9216.0f;
      float soft = 1.f / (1.f + expf(-(norm - thr)));
      float hard = (norm > thr) ? 1.f : 0.f;
      sind[t] = (hard - soft) + soft;
    }
    __syncthreads();
    stats[S_INDCH + t] = sind[t >> 2];
    float sc2 = bn2g[t] * (1.f / sqrtf(bn2v[t] + EPSF));
    stats[S_BN2SC + t] = sc2;
    stats[S_BN2SH + t] = bn2b[t] - bn2m[t] * sc2;
    if (t == 0) softmax3(al2, stats + S_PA2);
    return;
  }

  if (bid <= 512) {
    // ---- weight prep
    __shared__ __attribute__((aligned(16))) _Float16 lds[9 * WPS];
    __shared__ float sM, sSD, sP[3];
    int which = (bid - 1) >> 8, o = (bid - 1) & 255;
    if (t < 64) {
      float thr = thr_p[0];
      float mx = wave_max(stats[S_GMAX + t]);
      mx = __shfl(mx, 0);
      float norm = stats[S_GSUM + t] / mx / 9216.0f;
      float soft = 1.f / (1.f + expf(-(norm - thr)));
      float hard = (norm > thr) ? 1.f : 0.f;
      float iv = (hard - soft) + soft;
      float gate = (iv > 0.f) ? 1.f : 0.f;
      float ng = wave_sum(gate);
      float s = wave_sum(gate * stats[(which ? S_W2S : S_W1S) + t]);
      float q = wave_sum(gate * stats[(which ? S_W2Q : S_W1Q) + t]);
      if (t == 0) {
        float cnt = ng * 9216.0f;
        float m = s / cnt;
        float v = (q - cnt * m * m) / (cnt - 1.0f);
        sM = m; sSD = sqrtf(fmaxf(v, 0.f));
        softmax3(which ? wl2 : wl1, sP);
      }
    }
    __syncthreads();
    const float* w = (which ? w2 : w1) + (size_t)o * 2304;
    float mean = sM, sd = sSD + EPSF;
    float p0 = sP[0], p1 = sP[1], p2 = sP[2];
#pragma unroll
    for (int it = 0; it < 9; ++it) {
      int f = it * 256 + t;          // f = ci*9 + e
      float v = w[f];
      float wn = fminf(fmaxf((v - mean) / sd, -1.f), 1.f);
      float u0 = rintf((wn + 1.f) * 0.5f * 3.f) / 3.f;
      float u1 = rintf((wn + 1.f) * 0.5f * 15.f) / 15.f;
      float u2 = rintf((wn + 1.f) * 0.5f * 255.f) / 255.f;
      float mix = p0 * (2.f * u0 - 1.f) + p1 * (2.f * u1 - 1.f) + p2 * (2.f * u2 - 1.f);
      int ci = f / 9;
      int e = f - 9 * ci;
      lds[e * WPS + ci] = (_Float16)mix;
    }
    __syncthreads();
    _Float16* dst0 = (which ? wt2 : wt1) + o * 256;
#pragma unroll
    for (int it = 0; it < 2; ++it) {
      int qid = it * 256 + t;
      if (qid < 288) {
        int e = qid >> 5, c8 = (qid & 31) * 8;
        *(h8_t*)(dst0 + e * 65536 + c8) = *(const h8_t*)(lds + e * WPS + c8);
      }
    }
    return;
  }

  int ab = bid - 513;
  if (ab >= BB * HH) {
    // ---- border zeroing
    int b = ab - BB * HH;            // 0..127
    _Float16* img = (b >= BB ? a2 : a1) + (size_t)(b & 63) * PADIMG;
    uint64_t* u = (uint64_t*)img;
#pragma unroll
    for (int it = 0; it < 17; ++it) {
      int idx = it * 256 + t;          // 0..4351: rows 0 & 33 (full)
      int r33 = (idx >= 2176);
      u[(size_t)(r33 ? 33 * WP * 64 : 0) + (idx - (r33 ? 2176 : 0))] = 0ull;
    }
#pragma unroll
    for (int it = 0; it < 16; ++it) {
      int idx = it * 256 + t;          // 0..4095: cols 0/33 rows 1..32
      int p = idx >> 6;
      int y = 1 + (p >> 1), x = (p & 1) ? 33 : 0;
      u[(size_t)(y * WP + x) * 64 + (idx & 63)] = 0ull;
    }
    return;
  }

  // ---- act prep
  __shared__ __attribute__((aligned(16))) _Float16 lds[32 * APR_STRIDE];
  __shared__ float sBsc[256], sBsh[256], sPa[3];
  {
    float sc1 = bn1g[t] * (1.f / sqrtf(bn1v[t] + EPSF));
    sBsc[t] = sc1;
    sBsh[t] = bn1b[t] - bn1m[t] * sc1;
    if (t == 0) softmax3(al1, sPa);
  }
  __syncthreads();
  int n = ab >> 5, y = ab & 31;
  int x4 = (t & 7) * 4, c0 = t >> 3;
  float pa0 = sPa[0], pa1 = sPa[1], pa2 = sPa[2];
#pragma unroll
  for (int it = 0; it < 8; ++it) {
    int c = it * 32 + c0;
    const float* src = xin + ((size_t)(n * CC + c) * HH + y) * WW + x4;
    float4 v = *(const float4*)src;
    float sc = sBsc[c], sh = sBsh[c];
#pragma unroll
    for (int k = 0; k < 4; ++k) {
      float q = qmix_act((&v.x)[k] * sc + sh, pa0, pa1, pa2);
      lds[(x4 + k) * APR_STRIDE + c] = (_Float16)q;
    }
  }
  __syncthreads();
  _Float16* orow = a1 + ((size_t)(n * HP + (y + 1)) * WP + 1) * CC;
#pragma unroll
  for (int it = 0; it < 4; ++it) {
    int qid = it * 256 + t;
    int xx = qid >> 5, c8 = (qid & 31) * 8;
    *(h8_t*)(orow + xx * CC + c8) = *(const h8_t*)(lds + xx * APR_STRIDE + c8);
  }
}

// ---------------- implicit-GEMM conv, 128x128 tile, BK=64, fp16 MFMA ----------------
// kc OUTER / e INNER: the 9 taps re-touch the same act lines at reuse distance
// of 1 chunk -> act staging served from XCD-L2/L1 (per-block unique ~26 KB per
// kc-pass), shrinking the exposed vmcnt-drain latency.
template <bool SW>
__global__ __launch_bounds__(256) void k_conv(
    const _Float16* __restrict__ act,   // padded NHWC acts
    const _Float16* __restrict__ wts,   // [9][co][ci] fp16
    const float* __restrict__ stats,
    _Float16* __restrict__ a2out,
    const float* __restrict__ resid,
    float* __restrict__ out) {
  __shared__ __attribute__((aligned(16))) _Float16 As[128 * 64];
  __shared__ __attribute__((aligned(16))) _Float16 Ws[128 * 64];
  const int tid = threadIdx.x;
  const int lane = tid & 63, wid = tid >> 6;
  const int xcd = blockIdx.x & 7;
  const int j = blockIdx.x >> 3;          // 0..127
  const int blk_co = j >> 6;
  const int blk_m = xcd * 64 + (j & 63);

  const int srow = wid * 8 + (lane >> 3);
  const int g = (lane & 7) ^ (lane >> 3);
  int abase[4], wbase[4];
#pragma unroll
  for (int q = 0; q < 4; ++q) {
    int r = q * 32 + srow;
    int m = blk_m * 128 + r;
    int n = m >> 10, y = (m >> 5) & 31, x = m & 31;
    abase[q] = ((n * HP + y) * WP + x) * CC + g * 8;
    wbase[q] = (blk_co * 128 + r) * CC + g * 8;
  }

  const int wr = wid >> 1, wc = wid & 1;

  f4_t acc[4][4];
  const f4_t z4 = {0.f, 0.f, 0.f, 0.f};
#pragma unroll
  for (int i = 0; i < 4; ++i)
#pragma unroll
    for (int j2 = 0; j2 < 4; ++j2) acc[i][j2] = z4;

  int raoff[4], rboff[4];
#pragma unroll
  for (int i = 0; i < 4; ++i) {
    int ra = wr * 64 + i * 16 + (lane & 15);
    int sa = (lane >> 4) ^ (lane & 7);
    raoff[i] = ra * 64 + sa * 8;
    int rb = wc * 64 + i * 16 + (lane & 15);
    rboff[i] = rb * 64 + sa * 8;
  }

#pragma unroll 1
  for (int kc = 0; kc < 4; ++kc) {
    const int kb = kc * 64;
#pragma unroll
    for (int e = 0; e < 9; ++e) {
      const int kh = e / 3, kw = e - 3 * kh;
      const int ao = (kh * WP + kw) * CC + kb;
      const int wo = e * CC * CC + kb;
      __syncthreads();
#pragma unroll
      for (int q = 0; q < 4; ++q) {
        async_load16(As + (q * 32 + wid * 8) * 64, act + abase[q] + ao);
        async_load16(Ws + (q * 32 + wid * 8) * 64, wts + wbase[q] + wo);
      }
      __syncthreads();
      const _Float16* aT = SW ? Ws : As;
      const _Float16* bT = SW ? As : Ws;
#pragma unroll
      for (int kk = 0; kk < 2; ++kk) {
        h8_t fa[4], fb[4];
#pragma unroll
        for (int i = 0; i < 4; ++i) {
          fa[i] = *(const h8_t*)(aT + (raoff[i] ^ (kk * 32)));
          fb[i] = *(const h8_t*)(bT + (rboff[i] ^ (kk * 32)));
        }
#pragma unroll
        for (int i = 0; i < 4; ++i)
#pragma unroll
          for (int j2 = 0; j2 < 4; ++j2)
            acc[i][j2] = __builtin_amdgcn_mfma_f32_16x16x32_f16(fa[i], fb[j2], acc[i][j2], 0, 0, 0);
      }
    }
  }

  const int quad = lane >> 4;
  const int cq = lane & 15;
  if (!SW) {
    const float pa0 = stats[S_PA2], pa1 = stats[S_PA2 + 1], pa2 = stats[S_PA2 + 2];
#pragma unroll
    for (int j2 = 0; j2 < 4; ++j2) {
      const int co = blk_co * 128 + wc * 64 + j2 * 16 + cq;
      const float sc = stats[S_BN2SC + co];
      const float sh = stats[S_BN2SH + co];
      const float ic = stats[S_INDCH + co];
#pragma unroll
      for (int i = 0; i < 4; ++i) {
        const int mbase = blk_m * 128 + wr * 64 + i * 16 + quad * 4;
#pragma unroll
        for (int rg = 0; rg < 4; ++rg) {
          const int m = mbase + rg;
          const int n = m >> 10, y = (m >> 5) & 31, x = m & 31;
          float h = fmaxf(acc[i][j2][rg] * sc + sh, 0.f) * ic;
          float q = qmix_act(h, pa0, pa1, pa2);
          a2out[((size_t)(n * HP + y + 1) * WP + (x + 1)) * CC + co] = (_Float16)q;
        }
      }
    }
  } else {
#pragma unroll
    for (int j2 = 0; j2 < 4; ++j2) {
      const int m = blk_m * 128 + wc * 64 + j2 * 16 + cq;
      const int n = m >> 10, y = (m >> 5) & 31, x = m & 31;
#pragma unroll
      for (int i = 0; i < 4; ++i) {
        const int cobase = blk_co * 128 + wr * 64 + i * 16 + quad * 4;
#pragma unroll
        for (int rg = 0; rg < 4; ++rg) {
          const int co = cobase + rg;
          const int idx = ((n * CC + co) << 10) + (y << 5) + x;
          out[idx] = acc[i][j2][rg] + resid[idx];
        }
      }
    }
  }
}

extern "C" void kernel_launch(void* const* d_in, const int* in_sizes, int n_in,
                              void* d_out, int out_size, void* d_ws, size_t ws_size,
                              hipStream_t stream) {
  const float* x    = (const float*)d_in[0];
  const float* w1   = (const float*)d_in[1];
  const float* w2   = (const float*)d_in[2];
  const float* bn1g = (const float*)d_in[3];
  const float* bn1b = (const float*)d_in[4];
  const float* bn1m = (const float*)d_in[5];
  const float* bn1v = (const float*)d_in[6];
  const float* bn2g = (const float*)d_in[7];
  const float* bn2b = (const float*)d_in[8];
  const float* bn2m = (const float*)d_in[9];
  const float* bn2v = (const float*)d_in[10];
  const float* thr  = (const float*)d_in[11];
  const float* wl1  = (const float*)d_in[12];
  const float* al1  = (const float*)d_in[13];
  const float* wl2  = (const float*)d_in[14];
  const float* al2  = (const float*)d_in[15];

  char* ws = (char*)d_ws;
  float* stats = (float*)(ws + OFF_STATS);
  _Float16* a1 = (_Float16*)(ws + OFF_A1);
  _Float16* a2 = (_Float16*)(ws + OFF_A2);
  _Float16* wt1 = (_Float16*)(ws + OFF_W1T);
  _Float16* wt2 = (_Float16*)(ws + OFF_W2T);
  float* out = (float*)d_out;

  k_stats<<<128, 256, 0, stream>>>(w1, w2, stats);
  k_fused<<<1 + 512 + BB * HH + 128, 256, 0, stream>>>(
      w1, w2, x, thr, bn1g, bn1b, bn1m, bn1v, bn2g, bn2b, bn2m, bn2v,
      wl1, al1, wl2, al2, stats, wt1, wt2, a1, a2);
  k_conv<false><<<1024, 256, 0, stream>>>(a1, wt1, stats, a2, nullptr, nullptr);
  k_conv<true><<<1024, 256, 0, stream>>>(a2, wt2, stats, nullptr, x, out);
}